// Round 8
// baseline (195.649 us; speedup 1.0000x reference)
//
#include <hip/hip_runtime.h>
#include <hip/hip_bf16.h>

#define NN 100000      // nodes
#define FIN 256        // input features
#define FH 64          // hidden features
#define NEG 0.01f
#define NBUCK 256
#define BNODES ((NN + NBUCK - 1) / NBUCK)          // 391 nodes per coarse bucket
#define P1_CH 4096
#define WP 264         // LDS pitch for W^T (bf16 elems): 2-way bank conflict only
#define SRCMASK 0x1FFFF   // 17 bits (NN < 131072)

typedef __attribute__((ext_vector_type(8))) short short8x;
typedef __attribute__((ext_vector_type(4))) float f32x4;

// HW bf16 convert (compiler emits v_cvt_pk_bf16_f32 for adjacent pairs)
__device__ inline unsigned short f2bf_hw(float f) {
    __hip_bfloat16 h = __float2bfloat16(f);
    return __builtin_bit_cast(unsigned short, h);
}
__device__ inline unsigned pk2(float a, float b) {
    return (unsigned)f2bf_hw(a) | ((unsigned)f2bf_hw(b) << 16);
}
__device__ inline float bf2f(unsigned short s) {
    return __uint_as_float(((unsigned)s) << 16);
}
__device__ inline f32x4 ntload4(const float* p) {
    return __builtin_nontemporal_load((const f32x4*)p);
}

// ---------------------------------------------------------------------------
// ws layout (CSR path), bytes:
//   hbf[NN*FH] bf16 | nebf[NN*FH] bf16 (packed pairs int[E] staged here
//   pre-gather) | dinv[NN] f32 | cursor[NN+1] | bucket[E] | flag |
//   coarse_cnt[NBUCK] | coarse[NBUCK+1] | coarse_cursor[NBUCK]
// Fallback (ws too small): h f32 | ne f32 | deg | flag  (round-1 scatter)
// ---------------------------------------------------------------------------

__global__ void detect_zero_kernel(const int* __restrict__ ei32, int* __restrict__ flag,
                                   int* __restrict__ coarse_cnt) {
    const int t = threadIdx.x;
    coarse_cnt[t] = 0;
    if (t == 0) {
        int ok = 1;
        for (int k = 0; k < 64; ++k)
            if (ei32[2 * k + 1] != 0) { ok = 0; break; }
        *flag = ok;   // 1 => int64, 0 => int32
    }
}

__device__ inline long long load_idx(const void* p, long long i, int is64) {
    if (is64) return ((const long long*)p)[i];
    return (long long)((const int*)p)[i];
}
__device__ inline long long load_idx_nt(const void* p, long long i, int is64) {
    if (is64) return __builtin_nontemporal_load(((const long long*)p) + i);
    return (long long)__builtin_nontemporal_load(((const int*)p) + i);
}

// ---------------- bf16 MFMA GEMM: hbf = bf16( x @ W_conv ) ------------------
__global__ __launch_bounds__(256) void gemm_bf16_kernel(const float* __restrict__ x,
                                                        const float* __restrict__ W,
                                                        unsigned short* __restrict__ hbf) {
    __shared__ unsigned short Wt[FH * WP];   // [col][k], pitch WP

    for (int i = threadIdx.x; i < FIN * FH; i += 256) {
        int k = i >> 6, c = i & 63;
        Wt[c * WP + k] = f2bf_hw(W[i]);
    }
    __syncthreads();

    const int wv = threadIdx.x >> 6;
    const int lane = threadIdx.x & 63;
    const int c = lane & 15;
    const int eg = lane >> 4;

    const int row0 = (blockIdx.x * 4 + wv) * 16;
    int rowA = row0 + c;
    if (rowA >= NN) rowA = NN - 1;
    const float* aptr = x + (long long)rowA * FIN;

    f32x4 acc[4] = {{0,0,0,0},{0,0,0,0},{0,0,0,0},{0,0,0,0}};

#pragma unroll
    for (int kk = 0; kk < 8; ++kk) {
        const int kbase = kk * 32 + eg * 8;
        f32x4 f0 = ntload4(aptr + kbase);
        f32x4 f1 = ntload4(aptr + kbase + 4);
        union { short8x v; unsigned u[4]; } au;
        au.u[0] = pk2(f0[0], f0[1]);
        au.u[1] = pk2(f0[2], f0[3]);
        au.u[2] = pk2(f1[0], f1[1]);
        au.u[3] = pk2(f1[2], f1[3]);
#pragma unroll
        for (int cb = 0; cb < 4; ++cb) {
            short8x b = *(const short8x*)(&Wt[(cb * 16 + c) * WP + kbase]);
            acc[cb] = __builtin_amdgcn_mfma_f32_16x16x32_bf16(au.v, b, acc[cb], 0, 0, 0);
        }
    }

#pragma unroll
    for (int cb = 0; cb < 4; ++cb) {
#pragma unroll
        for (int r = 0; r < 4; ++r) {
            int rowO = row0 + eg * 4 + r;
            if (rowO < NN)
                hbf[(long long)rowO * FH + cb * 16 + c] = f2bf_hw(acc[cb][r]);
        }
    }
}

// ------------------------- CSR build ---------------------------------------

__global__ __launch_bounds__(256) void coarse_count_kernel(const void* __restrict__ ei,
                                                           int* __restrict__ coarse_cnt,
                                                           int E, const int* __restrict__ flag) {
    __shared__ int hist[NBUCK];
    const int t = threadIdx.x;
    hist[t] = 0;
    __syncthreads();
    const int is64 = *flag;
    for (long long e = (long long)blockIdx.x * 256 + t; e < E; e += (long long)gridDim.x * 256) {
        int d = (int)load_idx_nt(ei, (long long)E + e, is64);
        atomicAdd(&hist[(unsigned)d / BNODES], 1);
    }
    __syncthreads();
    if (hist[t]) atomicAdd(&coarse_cnt[t], hist[t]);
}

__global__ __launch_bounds__(256) void coarse_scan_kernel(const int* __restrict__ coarse_cnt,
                                                          int* __restrict__ coarse,
                                                          int* __restrict__ coarse_cursor) {
    const int t = threadIdx.x;
    const int lane = t & 63, w = t >> 6;
    int v = coarse_cnt[t];
    int incl = v;
#pragma unroll
    for (int m = 1; m < 64; m <<= 1) {
        int u = __shfl_up(incl, m, 64);
        if (lane >= m) incl += u;
    }
    __shared__ int wsum[4];
    if (lane == 63) wsum[w] = incl;
    __syncthreads();
    int woff = 0;
    for (int i = 0; i < w; ++i) woff += wsum[i];
    int ex = woff + incl - v;
    coarse[t] = ex;
    coarse_cursor[t] = ex;
    if (t == 255) coarse[NBUCK] = ex + v;   // = E
}

// P1: partition edges into 256 coarse buckets; packed (src | dlocal<<17) writes.
__global__ __launch_bounds__(256) void part_kernel(const void* __restrict__ ei,
                                                   int* __restrict__ coarse_cursor,
                                                   int* __restrict__ pairs,
                                                   int E, const int* __restrict__ flag) {
    __shared__ int hist[NBUCK];
    __shared__ int blkoff[NBUCK];
    const int t = threadIdx.x;
    hist[t] = 0;
    __syncthreads();
    const int is64 = *flag;
    const long long base = (long long)blockIdx.x * P1_CH;

    int pkv[16], bkt[16], rnk[16];
#pragma unroll
    for (int i = 0; i < 16; ++i) {
        long long e = base + i * 256 + t;
        if (e < E) {
            int s = (int)load_idx_nt(ei, e, is64);
            int d = (int)load_idx_nt(ei, (long long)E + e, is64);
            int b = (int)((unsigned)d / BNODES);
            int dl = d - b * BNODES;
            pkv[i] = s | (dl << 17);
            bkt[i] = b;
            rnk[i] = atomicAdd(&hist[b], 1);
        } else {
            bkt[i] = -1;
        }
    }
    __syncthreads();
    blkoff[t] = atomicAdd(&coarse_cursor[t], hist[t]);
    __syncthreads();
#pragma unroll
    for (int i = 0; i < 16; ++i) {
        if (bkt[i] >= 0)
            pairs[blkoff[bkt[i]] + rnk[i]] = pkv[i];
    }
}

// P2: per coarse bucket: LDS degree count + scan -> cursor/dinv, then place
// src into final CSR slots. No global atomics, no prescale.
__global__ __launch_bounds__(256) void place2_kernel(const int* __restrict__ pairs,
                                                     const int* __restrict__ coarse,
                                                     int* __restrict__ cursor,
                                                     float* __restrict__ dinv,
                                                     int* __restrict__ bucket) {
    __shared__ int cnt[BNODES];
    __shared__ int nstart[BNODES + 1];
    __shared__ int wsum[4];
    const int b = blockIdx.x, t = threadIdx.x;
    const int lane = t & 63, w = t >> 6;
    const int g0 = b * BNODES;
    const int nb = (NN - g0 < BNODES) ? (NN - g0) : BNODES;
    const int lo = coarse[b], hi = coarse[b + 1];

    for (int j = t; j < nb; j += 256) cnt[j] = 0;
    __syncthreads();

    // pass 1: local degree count
    for (int i = lo + t; i < hi; i += 256)
        atomicAdd(&cnt[pairs[i] >> 17], 1);
    __syncthreads();

    // exclusive scan of cnt[0..nb) -> nstart[0..nb]
    const int i0 = 2 * t, i1 = 2 * t + 1;
    const int v0 = (i0 < nb) ? cnt[i0] : 0;
    const int v1 = (i1 < nb) ? cnt[i1] : 0;
    const int s = v0 + v1;
    int incl = s;
#pragma unroll
    for (int m = 1; m < 64; m <<= 1) {
        int u = __shfl_up(incl, m, 64);
        if (lane >= m) incl += u;
    }
    if (lane == 63) wsum[w] = incl;
    __syncthreads();
    int woff = 0;
    for (int i = 0; i < w; ++i) woff += wsum[i];
    const int ex = woff + incl - s;
    if (i0 <= nb) nstart[i0] = ex;
    if (i1 <= nb) nstart[i1] = ex + v0;
    __syncthreads();

    // emit cursor + dinv (coalesced)
    for (int j = t; j <= nb; j += 256) {
        int g = g0 + j;
        if (g <= NN) cursor[g] = lo + nstart[j];
    }
    for (int j = t; j < nb; j += 256)
        dinv[g0 + j] = rsqrtf(1.0f + (float)(nstart[j + 1] - nstart[j]));

    // pass 2: place
    for (int j = t; j < nb; j += 256) cnt[j] = 0;
    __syncthreads();
    for (int i = lo + t; i < hi; i += 256) {
        int p = pairs[i];
        int local = p >> 17;
        int r = atomicAdd(&cnt[local], 1);
        bucket[lo + nstart[local] + r] = p & SRCMASK;
    }
}

// one wave per node, 8 edges in flight: pull-sum, self-loop + bias, leaky,
// bf16 output.
__global__ __launch_bounds__(256) void gather8_kernel(const unsigned short* __restrict__ hbf,
                                                      const float* __restrict__ dinv,
                                                      const int* __restrict__ cursor,
                                                      const int* __restrict__ bucket,
                                                      const float* __restrict__ b_conv,
                                                      unsigned short* __restrict__ nebf) {
    const int node = blockIdx.x * 4 + (threadIdx.x >> 6);
    if (node >= NN) return;
    const int lane = threadIdx.x & 63;
    const int sub = lane & 7;     // 8-bf16 chunk of the row
    const int eg = lane >> 3;     // edge slot (8)

    const int base = cursor[node];
    const int end  = cursor[node + 1];
    const float dd = dinv[node];

    float acc[8] = {0,0,0,0,0,0,0,0};
    for (int k = base + eg; k < end; k += 8) {
        int s = __builtin_nontemporal_load(&bucket[k]);
        float nrm = dinv[s] * dd;
        short8x hv = *(const short8x*)(hbf + (long long)s * FH + sub * 8);
#pragma unroll
        for (int j = 0; j < 8; ++j)
            acc[j] += bf2f((unsigned short)hv[j]) * nrm;
    }
#pragma unroll
    for (int m = 8; m < 64; m <<= 1) {
#pragma unroll
        for (int j = 0; j < 8; ++j) acc[j] += __shfl_xor(acc[j], m);
    }
    if (eg == 0) {
        short8x hs = *(const short8x*)(hbf + (long long)node * FH + sub * 8);
        float r[8];
#pragma unroll
        for (int j = 0; j < 8; ++j) {
            float v = acc[j] + bf2f((unsigned short)hs[j]) * dd * dd + b_conv[sub * 8 + j];
            r[j] = v >= 0.f ? v : NEG * v;
        }
        union { short8x v; unsigned u[4]; } ou;
        ou.u[0] = pk2(r[0], r[1]);
        ou.u[1] = pk2(r[2], r[3]);
        ou.u[2] = pk2(r[4], r[5]);
        ou.u[3] = pk2(r[6], r[7]);
        *(short8x*)(nebf + (long long)node * FH + sub * 8) = ou.v;
    }
}

// ------------------------- MLP head (bf16 ne) -------------------------------
__global__ __launch_bounds__(256) void mlp_bf16_kernel(const unsigned short* __restrict__ nebf,
                                                       const void* __restrict__ idx,
                                                       const float* __restrict__ W1,
                                                       const float* __restrict__ b1,
                                                       const float* __restrict__ W2,
                                                       const float* __restrict__ b2,
                                                       float* __restrict__ out,
                                                       int B, const int* __restrict__ flag) {
    const int lane = threadIdx.x & 63;
    const int wid = threadIdx.x >> 6;

    float w1a[16], w1b[16], b1r[16], w2r[16];
#pragma unroll
    for (int o = 0; o < 16; ++o) {
        w1a[o] = W1[lane * 16 + o];
        w1b[o] = W1[(64 + lane) * 16 + o];
        b1r[o] = b1[o];
        w2r[o] = W2[o];
    }
    const float b2v = b2[0];
    const int is64 = *flag;

    for (int pair = blockIdx.x * 4 + wid; pair < B; pair += gridDim.x * 4) {
        long long i0 = load_idx(idx, 2LL * pair, is64);
        long long i1 = load_idx(idx, 2LL * pair + 1, is64);
        float a = bf2f(nebf[i0 * FH + lane]);
        float b = bf2f(nebf[i1 * FH + lane]);

        float acc[16];
#pragma unroll
        for (int o = 0; o < 16; ++o) acc[o] = a * w1a[o] + b * w1b[o];
#pragma unroll
        for (int m = 1; m < 64; m <<= 1) {
#pragma unroll
            for (int o = 0; o < 16; ++o) acc[o] += __shfl_xor(acc[o], m, 64);
        }
        if (lane == 0) {
            float s = b2v;
#pragma unroll
            for (int o = 0; o < 16; ++o) {
                float z = acc[o] + b1r[o];
                z = z >= 0.f ? z : NEG * z;
                s += z * w2r[o];
            }
            out[pair] = 1.f / (1.f + expf(-s));
        }
    }
}

// ------------------------- fallback (round-1) path --------------------------

__global__ void detect_kernel(const int* __restrict__ ei32, int* __restrict__ flag) {
    if (blockIdx.x == 0 && threadIdx.x == 0) {
        int ok = 1;
        for (int k = 0; k < 64; ++k)
            if (ei32[2 * k + 1] != 0) { ok = 0; break; }
        *flag = ok;
    }
}

__global__ __launch_bounds__(256) void gemm_kernel(const float* __restrict__ x,
                                                   const float* __restrict__ W,
                                                   float* __restrict__ h) {
    __shared__ float xs[4 * FIN];
    __shared__ float part[4][4][FH];

    const int col = threadIdx.x & 63;
    const int kseg = threadIdx.x >> 6;

    float wreg[64];
#pragma unroll
    for (int kk = 0; kk < 64; ++kk)
        wreg[kk] = W[(kseg * 64 + kk) * FH + col];

    for (int row0 = blockIdx.x * 4; row0 < NN; row0 += gridDim.x * 4) {
        const float4* xv = (const float4*)(x + (long long)row0 * FIN);
        ((float4*)xs)[threadIdx.x] = xv[threadIdx.x];
        __syncthreads();

        float acc[4] = {0.f, 0.f, 0.f, 0.f};
#pragma unroll
        for (int kk = 0; kk < 64; ++kk) {
            const float w = wreg[kk];
            const int k = kseg * 64 + kk;
#pragma unroll
            for (int r = 0; r < 4; ++r)
                acc[r] += xs[r * FIN + k] * w;
        }
#pragma unroll
        for (int r = 0; r < 4; ++r) part[r][kseg][col] = acc[r];
        __syncthreads();

        const int row = threadIdx.x >> 6;
        float s = part[row][0][col] + part[row][1][col] + part[row][2][col] + part[row][3][col];
        h[(long long)(row0 + row) * FH + col] = s;
        __syncthreads();
    }
}

__global__ __launch_bounds__(256) void init_kernel(float* __restrict__ ne,
                                                   float* __restrict__ deg,
                                                   const float* __restrict__ b_conv) {
    int idx = blockIdx.x * 256 + threadIdx.x;
    if (idx < NN * FH) ne[idx] = b_conv[idx & (FH - 1)];
    if (idx < NN) deg[idx] = 1.0f;
}

__global__ __launch_bounds__(256) void deg_kernel(const void* __restrict__ ei,
                                                  float* __restrict__ deg,
                                                  int E, const int* __restrict__ flag) {
    int e = blockIdx.x * 256 + threadIdx.x;
    if (e >= E) return;
    long long d = load_idx(ei, (long long)E + e, *flag);
    atomicAdd(&deg[d], 1.0f);
}

__global__ __launch_bounds__(256) void rsqrt_kernel(float* __restrict__ deg) {
    int i = blockIdx.x * 256 + threadIdx.x;
    if (i < NN) deg[i] = rsqrtf(deg[i]);
}

__global__ __launch_bounds__(256) void selfloop_kernel(const float* __restrict__ h,
                                                       const float* __restrict__ dinv,
                                                       float* __restrict__ ne) {
    int idx = blockIdx.x * 256 + threadIdx.x;
    if (idx >= NN * FH) return;
    int i = idx >> 6;
    float di = dinv[i];
    ne[idx] += h[idx] * di * di;
}

__global__ __launch_bounds__(256) void edge_agg_kernel(const void* __restrict__ ei,
                                                       const float* __restrict__ dinv,
                                                       const float* __restrict__ h,
                                                       float* __restrict__ ne,
                                                       int E, const int* __restrict__ flag) {
    long long t = (long long)blockIdx.x * 256 + threadIdx.x;
    long long e = t >> 4;
    int sub = (int)(t & 15);
    if (e >= E) return;
    int is64 = *flag;
    long long s = load_idx(ei, e, is64);
    long long d = load_idx(ei, (long long)E + e, is64);
    float nrm = dinv[s] * dinv[d];
    float4 hv = *(const float4*)(h + s * FH + sub * 4);
    float* np_ = ne + d * FH + sub * 4;
    atomicAdd(np_ + 0, hv.x * nrm);
    atomicAdd(np_ + 1, hv.y * nrm);
    atomicAdd(np_ + 2, hv.z * nrm);
    atomicAdd(np_ + 3, hv.w * nrm);
}

__global__ __launch_bounds__(256) void mlp_kernel(const float* __restrict__ ne,
                                                  const void* __restrict__ idx,
                                                  const float* __restrict__ W1,
                                                  const float* __restrict__ b1,
                                                  const float* __restrict__ W2,
                                                  const float* __restrict__ b2,
                                                  float* __restrict__ out,
                                                  int B, const int* __restrict__ flag,
                                                  int pre_act) {
    const int lane = threadIdx.x & 63;
    const int wid = threadIdx.x >> 6;

    float w1a[16], w1b[16], b1r[16], w2r[16];
#pragma unroll
    for (int o = 0; o < 16; ++o) {
        w1a[o] = W1[lane * 16 + o];
        w1b[o] = W1[(64 + lane) * 16 + o];
        b1r[o] = b1[o];
        w2r[o] = W2[o];
    }
    const float b2v = b2[0];
    const int is64 = *flag;

    for (int pair = blockIdx.x * 4 + wid; pair < B; pair += gridDim.x * 4) {
        long long i0 = load_idx(idx, 2LL * pair, is64);
        long long i1 = load_idx(idx, 2LL * pair + 1, is64);
        float a = ne[i0 * FH + lane];
        float b = ne[i1 * FH + lane];
        if (pre_act) {
            a = a >= 0.f ? a : NEG * a;
            b = b >= 0.f ? b : NEG * b;
        }

        float acc[16];
#pragma unroll
        for (int o = 0; o < 16; ++o) acc[o] = a * w1a[o] + b * w1b[o];
#pragma unroll
        for (int m = 1; m < 64; m <<= 1) {
#pragma unroll
            for (int o = 0; o < 16; ++o) acc[o] += __shfl_xor(acc[o], m, 64);
        }
        if (lane == 0) {
            float s = b2v;
#pragma unroll
            for (int o = 0; o < 16; ++o) {
                float z = acc[o] + b1r[o];
                z = z >= 0.f ? z : NEG * z;
                s += z * w2r[o];
            }
            out[pair] = 1.f / (1.f + expf(-s));
        }
    }
}

extern "C" void kernel_launch(void* const* d_in, const int* in_sizes, int n_in,
                              void* d_out, int out_size, void* d_ws, size_t ws_size,
                              hipStream_t stream) {
    const float* x      = (const float*)d_in[0];
    const void*  ei     = d_in[1];
    const void*  index  = d_in[2];
    const float* W_conv = (const float*)d_in[3];
    const float* b_conv = (const float*)d_in[4];
    const float* W1     = (const float*)d_in[5];
    const float* b1     = (const float*)d_in[6];
    const float* W2     = (const float*)d_in[7];
    const float* b2     = (const float*)d_in[8];
    float* out = (float*)d_out;

    const int E = in_sizes[1] / 2;   // 1.6M
    const int B = in_sizes[2] / 2;   // 16384

    const size_t need_new = (size_t)NN * FH * 2 * 2
                          + ((size_t)NN + (NN + 1) + (size_t)E
                             + 1 + NBUCK + (NBUCK + 1) + NBUCK) * 4;

    if (ws_size >= need_new) {
        unsigned short* hbf  = (unsigned short*)d_ws;
        unsigned short* nebf = hbf + (long long)NN * FH;
        float* dinv     = (float*)(nebf + (long long)NN * FH);
        int*   cursor   = (int*)(dinv + NN);          // NN+1 entries
        int*   bucket   = cursor + (NN + 1);
        int*   flag     = bucket + E;
        int*   coarse_cnt    = flag + 1;
        int*   coarse        = coarse_cnt + NBUCK;    // NBUCK+1
        int*   coarse_cursor = coarse + (NBUCK + 1);
        int*   pairs    = (int*)nebf;                 // staged in dead ne buffer

        detect_zero_kernel<<<1, 256, 0, stream>>>((const int*)ei, flag, coarse_cnt);
        gemm_bf16_kernel<<<(NN + 63) / 64, 256, 0, stream>>>(x, W_conv, hbf);
        coarse_count_kernel<<<256, 256, 0, stream>>>(ei, coarse_cnt, E, flag);
        coarse_scan_kernel<<<1, 256, 0, stream>>>(coarse_cnt, coarse, coarse_cursor);
        part_kernel<<<(E + P1_CH - 1) / P1_CH, 256, 0, stream>>>(ei, coarse_cursor, pairs, E, flag);
        place2_kernel<<<NBUCK, 256, 0, stream>>>(pairs, coarse, cursor, dinv, bucket);
        gather8_kernel<<<(NN + 3) / 4, 256, 0, stream>>>(hbf, dinv, cursor, bucket, b_conv, nebf);
        mlp_bf16_kernel<<<512, 256, 0, stream>>>(nebf, index, W1, b1, W2, b2, out, B, flag);
    } else {
        // fallback: round-1 atomic scatter (fp32)
        float* h   = (float*)d_ws;
        float* ne  = h + (long long)NN * FH;
        float* deg = ne + (long long)NN * FH;
        int* flag  = (int*)(deg + NN);

        detect_kernel<<<1, 64, 0, stream>>>((const int*)ei, flag);
        init_kernel<<<(NN * FH + 255) / 256, 256, 0, stream>>>(ne, deg, b_conv);
        gemm_kernel<<<2048, 256, 0, stream>>>(x, W_conv, h);
        deg_kernel<<<(E + 255) / 256, 256, 0, stream>>>(ei, deg, E, flag);
        rsqrt_kernel<<<(NN + 255) / 256, 256, 0, stream>>>(deg);
        selfloop_kernel<<<(NN * FH + 255) / 256, 256, 0, stream>>>(h, deg, ne);
        edge_agg_kernel<<<(int)(((long long)E * 16 + 255) / 256), 256, 0, stream>>>(ei, deg, h, ne, E, flag);
        mlp_kernel<<<512, 256, 0, stream>>>(ne, index, W1, b1, W2, b2, out, B, flag, 1);
    }
}

// Round 9
// 174.054 us; speedup vs baseline: 1.1241x; 1.1241x over previous
//
#include <hip/hip_runtime.h>
#include <hip/hip_bf16.h>

#define NN 100000      // nodes
#define FIN 256        // input features
#define FH 64          // hidden features
#define NEG 0.01f
#define NBUCK 256
#define BNODES ((NN + NBUCK - 1) / NBUCK)          // 391 nodes per coarse bucket
#define P1_CH 4096
#define WP 264         // LDS pitch for W^T (bf16 elems): 2-way bank conflict only
#define SRCMASK 0x1FFFF   // 17 bits (NN < 131072)

typedef __attribute__((ext_vector_type(8))) short short8x;
typedef __attribute__((ext_vector_type(4))) float f32x4;

// HW bf16 convert (compiler packs adjacent pairs into v_cvt_pk_bf16_f32)
__device__ inline unsigned short f2bf_hw(float f) {
    __hip_bfloat16 h = __float2bfloat16(f);
    return __builtin_bit_cast(unsigned short, h);
}
__device__ inline float bf2f(unsigned short s) {
    return __uint_as_float(((unsigned)s) << 16);
}

// ---------------------------------------------------------------------------
// ws layout (CSR path), bytes:
//   hbf[NN*FH] bf16 | ne[NN*FH] f32 (packed pairs int[E] staged here
//   pre-gather) | dinv[NN] | cursor[NN+1] | bucket[E] | flag |
//   coarse_cnt[NBUCK] | coarse[NBUCK+1] | coarse_cursor[NBUCK]
// Fallback (ws too small): h f32 | ne f32 | deg | flag  (round-1 scatter)
// ---------------------------------------------------------------------------

__global__ void detect_zero_kernel(const int* __restrict__ ei32, int* __restrict__ flag,
                                   int* __restrict__ coarse_cnt) {
    const int t = threadIdx.x;
    coarse_cnt[t] = 0;
    if (t == 0) {
        int ok = 1;
        for (int k = 0; k < 64; ++k)
            if (ei32[2 * k + 1] != 0) { ok = 0; break; }
        *flag = ok;   // 1 => int64, 0 => int32
    }
}

__device__ inline long long load_idx(const void* p, long long i, int is64) {
    if (is64) return ((const long long*)p)[i];
    return (long long)((const int*)p)[i];
}

// ---------------- bf16 MFMA GEMM: hbf = bf16( x @ W_conv ) ------------------
__global__ __launch_bounds__(256) void gemm_bf16_kernel(const float* __restrict__ x,
                                                        const float* __restrict__ W,
                                                        unsigned short* __restrict__ hbf) {
    __shared__ unsigned short Wt[FH * WP];   // [col][k], pitch WP

    for (int i = threadIdx.x; i < FIN * FH; i += 256) {
        int k = i >> 6, c = i & 63;
        Wt[c * WP + k] = f2bf_hw(W[i]);
    }
    __syncthreads();

    const int wv = threadIdx.x >> 6;
    const int lane = threadIdx.x & 63;
    const int c = lane & 15;
    const int eg = lane >> 4;

    const int row0 = (blockIdx.x * 4 + wv) * 16;
    int rowA = row0 + c;
    if (rowA >= NN) rowA = NN - 1;
    const float* aptr = x + (long long)rowA * FIN;

    f32x4 acc[4] = {{0,0,0,0},{0,0,0,0},{0,0,0,0},{0,0,0,0}};

#pragma unroll
    for (int kk = 0; kk < 8; ++kk) {
        const int kbase = kk * 32 + eg * 8;
        float4 f0 = *(const float4*)(aptr + kbase);
        float4 f1 = *(const float4*)(aptr + kbase + 4);
        short8x a;
        a[0] = (short)f2bf_hw(f0.x); a[1] = (short)f2bf_hw(f0.y);
        a[2] = (short)f2bf_hw(f0.z); a[3] = (short)f2bf_hw(f0.w);
        a[4] = (short)f2bf_hw(f1.x); a[5] = (short)f2bf_hw(f1.y);
        a[6] = (short)f2bf_hw(f1.z); a[7] = (short)f2bf_hw(f1.w);
#pragma unroll
        for (int cb = 0; cb < 4; ++cb) {
            short8x b = *(const short8x*)(&Wt[(cb * 16 + c) * WP + kbase]);
            acc[cb] = __builtin_amdgcn_mfma_f32_16x16x32_bf16(a, b, acc[cb], 0, 0, 0);
        }
    }

#pragma unroll
    for (int cb = 0; cb < 4; ++cb) {
#pragma unroll
        for (int r = 0; r < 4; ++r) {
            int rowO = row0 + eg * 4 + r;
            if (rowO < NN)
                hbf[(long long)rowO * FH + cb * 16 + c] = f2bf_hw(acc[cb][r]);
        }
    }
}

// ------------------------- CSR build ---------------------------------------

__global__ __launch_bounds__(256) void coarse_count_kernel(const void* __restrict__ ei,
                                                           int* __restrict__ coarse_cnt,
                                                           int E, const int* __restrict__ flag) {
    __shared__ int hist[NBUCK];
    const int t = threadIdx.x;
    hist[t] = 0;
    __syncthreads();
    const int is64 = *flag;
    for (long long e = (long long)blockIdx.x * 256 + t; e < E; e += (long long)gridDim.x * 256) {
        int d = (int)load_idx(ei, (long long)E + e, is64);
        atomicAdd(&hist[(unsigned)d / BNODES], 1);
    }
    __syncthreads();
    if (hist[t]) atomicAdd(&coarse_cnt[t], hist[t]);
}

__global__ __launch_bounds__(256) void coarse_scan_kernel(const int* __restrict__ coarse_cnt,
                                                          int* __restrict__ coarse,
                                                          int* __restrict__ coarse_cursor) {
    const int t = threadIdx.x;
    const int lane = t & 63, w = t >> 6;
    int v = coarse_cnt[t];
    int incl = v;
#pragma unroll
    for (int m = 1; m < 64; m <<= 1) {
        int u = __shfl_up(incl, m, 64);
        if (lane >= m) incl += u;
    }
    __shared__ int wsum[4];
    if (lane == 63) wsum[w] = incl;
    __syncthreads();
    int woff = 0;
    for (int i = 0; i < w; ++i) woff += wsum[i];
    int ex = woff + incl - v;
    coarse[t] = ex;
    coarse_cursor[t] = ex;
    if (t == 255) coarse[NBUCK] = ex + v;   // = E
}

// P1: partition edges into 256 coarse buckets; packed (src | dlocal<<17) writes.
__global__ __launch_bounds__(256) void part_kernel(const void* __restrict__ ei,
                                                   int* __restrict__ coarse_cursor,
                                                   int* __restrict__ pairs,
                                                   int E, const int* __restrict__ flag) {
    __shared__ int hist[NBUCK];
    __shared__ int blkoff[NBUCK];
    const int t = threadIdx.x;
    hist[t] = 0;
    __syncthreads();
    const int is64 = *flag;
    const long long base = (long long)blockIdx.x * P1_CH;

    int pkv[16], bkt[16], rnk[16];
#pragma unroll
    for (int i = 0; i < 16; ++i) {
        long long e = base + i * 256 + t;
        if (e < E) {
            int s = (int)load_idx(ei, e, is64);
            int d = (int)load_idx(ei, (long long)E + e, is64);
            int b = (int)((unsigned)d / BNODES);
            int dl = d - b * BNODES;
            pkv[i] = s | (dl << 17);
            bkt[i] = b;
            rnk[i] = atomicAdd(&hist[b], 1);
        } else {
            bkt[i] = -1;
        }
    }
    __syncthreads();
    blkoff[t] = atomicAdd(&coarse_cursor[t], hist[t]);
    __syncthreads();
#pragma unroll
    for (int i = 0; i < 16; ++i) {
        if (bkt[i] >= 0)
            pairs[blkoff[bkt[i]] + rnk[i]] = pkv[i];
    }
}

// P2: per coarse bucket: LDS degree count + scan -> cursor/dinv, then place
// src into final CSR slots. No global atomics.
__global__ __launch_bounds__(256) void place2_kernel(const int* __restrict__ pairs,
                                                     const int* __restrict__ coarse,
                                                     int* __restrict__ cursor,
                                                     float* __restrict__ dinv,
                                                     int* __restrict__ bucket) {
    __shared__ int cnt[BNODES];
    __shared__ int nstart[BNODES + 1];
    __shared__ int wsum[4];
    const int b = blockIdx.x, t = threadIdx.x;
    const int lane = t & 63, w = t >> 6;
    const int g0 = b * BNODES;
    const int nb = (NN - g0 < BNODES) ? (NN - g0) : BNODES;
    const int lo = coarse[b], hi = coarse[b + 1];

    for (int j = t; j < nb; j += 256) cnt[j] = 0;
    __syncthreads();

    // pass 1: local degree count
    for (int i = lo + t; i < hi; i += 256)
        atomicAdd(&cnt[pairs[i] >> 17], 1);
    __syncthreads();

    // exclusive scan of cnt[0..nb) -> nstart[0..nb]
    const int i0 = 2 * t, i1 = 2 * t + 1;
    const int v0 = (i0 < nb) ? cnt[i0] : 0;
    const int v1 = (i1 < nb) ? cnt[i1] : 0;
    const int s = v0 + v1;
    int incl = s;
#pragma unroll
    for (int m = 1; m < 64; m <<= 1) {
        int u = __shfl_up(incl, m, 64);
        if (lane >= m) incl += u;
    }
    if (lane == 63) wsum[w] = incl;
    __syncthreads();
    int woff = 0;
    for (int i = 0; i < w; ++i) woff += wsum[i];
    const int ex = woff + incl - s;
    if (i0 <= nb) nstart[i0] = ex;
    if (i1 <= nb) nstart[i1] = ex + v0;
    __syncthreads();

    // emit cursor + dinv (coalesced)
    for (int j = t; j <= nb; j += 256) {
        int g = g0 + j;
        if (g <= NN) cursor[g] = lo + nstart[j];
    }
    for (int j = t; j < nb; j += 256)
        dinv[g0 + j] = rsqrtf(1.0f + (float)(nstart[j + 1] - nstart[j]));

    // pass 2: place
    for (int j = t; j < nb; j += 256) cnt[j] = 0;
    __syncthreads();
    for (int i = lo + t; i < hi; i += 256) {
        int p = pairs[i];
        int local = p >> 17;
        int r = atomicAdd(&cnt[local], 1);
        bucket[lo + nstart[local] + r] = p & SRCMASK;
    }
}

// one wave per node, 8 edges in flight: pull-sum, self-loop + bias, leaky.
// (exact R6 form: proven 59 us)
__global__ __launch_bounds__(256) void gather8_kernel(const unsigned short* __restrict__ hbf,
                                                      const float* __restrict__ dinv,
                                                      const int* __restrict__ cursor,
                                                      const int* __restrict__ bucket,
                                                      const float* __restrict__ b_conv,
                                                      float* __restrict__ ne) {
    const int node = blockIdx.x * 4 + (threadIdx.x >> 6);
    if (node >= NN) return;
    const int lane = threadIdx.x & 63;
    const int sub = lane & 7;     // 8-bf16 chunk of the row
    const int eg = lane >> 3;     // edge slot (8)

    const int base = cursor[node];
    const int end  = cursor[node + 1];
    const float dd = dinv[node];

    float acc[8] = {0,0,0,0,0,0,0,0};
    for (int k = base + eg; k < end; k += 8) {
        int s = bucket[k];
        float nrm = dinv[s] * dd;
        short8x hv = *(const short8x*)(hbf + (long long)s * FH + sub * 8);
#pragma unroll
        for (int j = 0; j < 8; ++j)
            acc[j] += bf2f((unsigned short)hv[j]) * nrm;
    }
#pragma unroll
    for (int m = 8; m < 64; m <<= 1) {
#pragma unroll
        for (int j = 0; j < 8; ++j) acc[j] += __shfl_xor(acc[j], m);
    }
    if (eg == 0) {
        short8x hs = *(const short8x*)(hbf + (long long)node * FH + sub * 8);
        float r[8];
#pragma unroll
        for (int j = 0; j < 8; ++j) {
            float v = acc[j] + bf2f((unsigned short)hs[j]) * dd * dd + b_conv[sub * 8 + j];
            r[j] = v >= 0.f ? v : NEG * v;
        }
        float4* o = (float4*)(ne + (long long)node * FH + sub * 8);
        o[0] = make_float4(r[0], r[1], r[2], r[3]);
        o[1] = make_float4(r[4], r[5], r[6], r[7]);
    }
}

// ------------------------- fallback (round-1) path --------------------------

__global__ void detect_kernel(const int* __restrict__ ei32, int* __restrict__ flag) {
    if (blockIdx.x == 0 && threadIdx.x == 0) {
        int ok = 1;
        for (int k = 0; k < 64; ++k)
            if (ei32[2 * k + 1] != 0) { ok = 0; break; }
        *flag = ok;
    }
}

__global__ __launch_bounds__(256) void gemm_kernel(const float* __restrict__ x,
                                                   const float* __restrict__ W,
                                                   float* __restrict__ h) {
    __shared__ float xs[4 * FIN];
    __shared__ float part[4][4][FH];

    const int col = threadIdx.x & 63;
    const int kseg = threadIdx.x >> 6;

    float wreg[64];
#pragma unroll
    for (int kk = 0; kk < 64; ++kk)
        wreg[kk] = W[(kseg * 64 + kk) * FH + col];

    for (int row0 = blockIdx.x * 4; row0 < NN; row0 += gridDim.x * 4) {
        const float4* xv = (const float4*)(x + (long long)row0 * FIN);
        ((float4*)xs)[threadIdx.x] = xv[threadIdx.x];
        __syncthreads();

        float acc[4] = {0.f, 0.f, 0.f, 0.f};
#pragma unroll
        for (int kk = 0; kk < 64; ++kk) {
            const float w = wreg[kk];
            const int k = kseg * 64 + kk;
#pragma unroll
            for (int r = 0; r < 4; ++r)
                acc[r] += xs[r * FIN + k] * w;
        }
#pragma unroll
        for (int r = 0; r < 4; ++r) part[r][kseg][col] = acc[r];
        __syncthreads();

        const int row = threadIdx.x >> 6;
        float s = part[row][0][col] + part[row][1][col] + part[row][2][col] + part[row][3][col];
        h[(long long)(row0 + row) * FH + col] = s;
        __syncthreads();
    }
}

__global__ __launch_bounds__(256) void init_kernel(float* __restrict__ ne,
                                                   float* __restrict__ deg,
                                                   const float* __restrict__ b_conv) {
    int idx = blockIdx.x * 256 + threadIdx.x;
    if (idx < NN * FH) ne[idx] = b_conv[idx & (FH - 1)];
    if (idx < NN) deg[idx] = 1.0f;
}

__global__ __launch_bounds__(256) void deg_kernel(const void* __restrict__ ei,
                                                  float* __restrict__ deg,
                                                  int E, const int* __restrict__ flag) {
    int e = blockIdx.x * 256 + threadIdx.x;
    if (e >= E) return;
    long long d = load_idx(ei, (long long)E + e, *flag);
    atomicAdd(&deg[d], 1.0f);
}

__global__ __launch_bounds__(256) void rsqrt_kernel(float* __restrict__ deg) {
    int i = blockIdx.x * 256 + threadIdx.x;
    if (i < NN) deg[i] = rsqrtf(deg[i]);
}

__global__ __launch_bounds__(256) void selfloop_kernel(const float* __restrict__ h,
                                                       const float* __restrict__ dinv,
                                                       float* __restrict__ ne) {
    int idx = blockIdx.x * 256 + threadIdx.x;
    if (idx >= NN * FH) return;
    int i = idx >> 6;
    float di = dinv[i];
    ne[idx] += h[idx] * di * di;
}

__global__ __launch_bounds__(256) void edge_agg_kernel(const void* __restrict__ ei,
                                                       const float* __restrict__ dinv,
                                                       const float* __restrict__ h,
                                                       float* __restrict__ ne,
                                                       int E, const int* __restrict__ flag) {
    long long t = (long long)blockIdx.x * 256 + threadIdx.x;
    long long e = t >> 4;
    int sub = (int)(t & 15);
    if (e >= E) return;
    int is64 = *flag;
    long long s = load_idx(ei, e, is64);
    long long d = load_idx(ei, (long long)E + e, is64);
    float nrm = dinv[s] * dinv[d];
    float4 hv = *(const float4*)(h + s * FH + sub * 4);
    float* np_ = ne + d * FH + sub * 4;
    atomicAdd(np_ + 0, hv.x * nrm);
    atomicAdd(np_ + 1, hv.y * nrm);
    atomicAdd(np_ + 2, hv.z * nrm);
    atomicAdd(np_ + 3, hv.w * nrm);
}

// ------------------------- MLP head -----------------------------------------
__global__ __launch_bounds__(256) void mlp_kernel(const float* __restrict__ ne,
                                                  const void* __restrict__ idx,
                                                  const float* __restrict__ W1,
                                                  const float* __restrict__ b1,
                                                  const float* __restrict__ W2,
                                                  const float* __restrict__ b2,
                                                  float* __restrict__ out,
                                                  int B, const int* __restrict__ flag,
                                                  int pre_act) {
    const int lane = threadIdx.x & 63;
    const int wid = threadIdx.x >> 6;

    float w1a[16], w1b[16], b1r[16], w2r[16];
#pragma unroll
    for (int o = 0; o < 16; ++o) {
        w1a[o] = W1[lane * 16 + o];
        w1b[o] = W1[(64 + lane) * 16 + o];
        b1r[o] = b1[o];
        w2r[o] = W2[o];
    }
    const float b2v = b2[0];
    const int is64 = *flag;

    for (int pair = blockIdx.x * 4 + wid; pair < B; pair += gridDim.x * 4) {
        long long i0 = load_idx(idx, 2LL * pair, is64);
        long long i1 = load_idx(idx, 2LL * pair + 1, is64);
        float a = ne[i0 * FH + lane];
        float b = ne[i1 * FH + lane];
        if (pre_act) {
            a = a >= 0.f ? a : NEG * a;
            b = b >= 0.f ? b : NEG * b;
        }

        float acc[16];
#pragma unroll
        for (int o = 0; o < 16; ++o) acc[o] = a * w1a[o] + b * w1b[o];
#pragma unroll
        for (int m = 1; m < 64; m <<= 1) {
#pragma unroll
            for (int o = 0; o < 16; ++o) acc[o] += __shfl_xor(acc[o], m, 64);
        }
        if (lane == 0) {
            float s = b2v;
#pragma unroll
            for (int o = 0; o < 16; ++o) {
                float z = acc[o] + b1r[o];
                z = z >= 0.f ? z : NEG * z;
                s += z * w2r[o];
            }
            out[pair] = 1.f / (1.f + expf(-s));
        }
    }
}

extern "C" void kernel_launch(void* const* d_in, const int* in_sizes, int n_in,
                              void* d_out, int out_size, void* d_ws, size_t ws_size,
                              hipStream_t stream) {
    const float* x      = (const float*)d_in[0];
    const void*  ei     = d_in[1];
    const void*  index  = d_in[2];
    const float* W_conv = (const float*)d_in[3];
    const float* b_conv = (const float*)d_in[4];
    const float* W1     = (const float*)d_in[5];
    const float* b1     = (const float*)d_in[6];
    const float* W2     = (const float*)d_in[7];
    const float* b2     = (const float*)d_in[8];
    float* out = (float*)d_out;

    const int E = in_sizes[1] / 2;   // 1.6M
    const int B = in_sizes[2] / 2;   // 16384

    const size_t need_new = (size_t)NN * FH * 2
                          + ((size_t)NN * FH + NN + (NN + 1) + (size_t)E
                             + 1 + NBUCK + (NBUCK + 1) + NBUCK) * 4;

    if (ws_size >= need_new) {
        unsigned short* hbf = (unsigned short*)d_ws;
        float* ne       = (float*)(hbf + (long long)NN * FH);
        float* dinv     = ne + (long long)NN * FH;
        int*   cursor   = (int*)(dinv + NN);          // NN+1 entries
        int*   bucket   = cursor + (NN + 1);
        int*   flag     = bucket + E;
        int*   coarse_cnt    = flag + 1;
        int*   coarse        = coarse_cnt + NBUCK;    // NBUCK+1
        int*   coarse_cursor = coarse + (NBUCK + 1);
        int*   pairs    = (int*)ne;                   // staged in dead ne buffer

        detect_zero_kernel<<<1, 256, 0, stream>>>((const int*)ei, flag, coarse_cnt);
        gemm_bf16_kernel<<<(NN + 63) / 64, 256, 0, stream>>>(x, W_conv, hbf);
        coarse_count_kernel<<<256, 256, 0, stream>>>(ei, coarse_cnt, E, flag);
        coarse_scan_kernel<<<1, 256, 0, stream>>>(coarse_cnt, coarse, coarse_cursor);
        part_kernel<<<(E + P1_CH - 1) / P1_CH, 256, 0, stream>>>(ei, coarse_cursor, pairs, E, flag);
        place2_kernel<<<NBUCK, 256, 0, stream>>>(pairs, coarse, cursor, dinv, bucket);
        gather8_kernel<<<(NN + 3) / 4, 256, 0, stream>>>(hbf, dinv, cursor, bucket, b_conv, ne);
        mlp_kernel<<<512, 256, 0, stream>>>(ne, index, W1, b1, W2, b2, out, B, flag, 0);
    } else {
        // fallback: round-1 atomic scatter (fp32)
        float* h   = (float*)d_ws;
        float* ne  = h + (long long)NN * FH;
        float* deg = ne + (long long)NN * FH;
        int* flag  = (int*)(deg + NN);

        detect_kernel<<<1, 64, 0, stream>>>((const int*)ei, flag);
        init_kernel<<<(NN * FH + 255) / 256, 256, 0, stream>>>(ne, deg, b_conv);
        gemm_kernel<<<2048, 256, 0, stream>>>(x, W_conv, h);
        deg_kernel<<<(E + 255) / 256, 256, 0, stream>>>(ei, deg, E, flag);
        rsqrt_kernel<<<(NN + 255) / 256, 256, 0, stream>>>(deg);
        selfloop_kernel<<<(NN * FH + 255) / 256, 256, 0, stream>>>(h, deg, ne);
        edge_agg_kernel<<<(int)(((long long)E * 16 + 255) / 256), 256, 0, stream>>>(ei, deg, h, ne, E, flag);
        mlp_kernel<<<512, 256, 0, stream>>>(ne, index, W1, b1, W2, b2, out, B, flag, 1);
    }
}

// Round 10
// 162.475 us; speedup vs baseline: 1.2042x; 1.0713x over previous
//
#include <hip/hip_runtime.h>
#include <hip/hip_bf16.h>

#define NN 100000      // nodes
#define FIN 256        // input features
#define FH 64          // hidden features
#define NEG 0.01f
#define NBUCK 256
#define BNODES ((NN + NBUCK - 1) / NBUCK)          // 391 nodes per coarse bucket
#define P1_CH 4096
#define WP 264         // LDS pitch for W^T (bf16 elems): 2-way bank conflict only
#define SRCMASK 0x1FFFF   // 17 bits (NN < 131072)
#define NCB 256        // count blocks
#define GB3 521        // gemm blocks per fused phase (3*521 = 1563 = ceil(NN/64))

typedef __attribute__((ext_vector_type(8))) short short8x;
typedef __attribute__((ext_vector_type(4))) float f32x4;

__device__ inline unsigned short f2bf_hw(float f) {
    __hip_bfloat16 h = __float2bfloat16(f);
    return __builtin_bit_cast(unsigned short, h);
}
__device__ inline float bf2f(unsigned short s) {
    return __uint_as_float(((unsigned)s) << 16);
}

__device__ inline long long load_idx(const void* p, long long i, int is64) {
    if (is64) return ((const long long*)p)[i];
    return (long long)((const int*)p)[i];
}

// wave-ballot int64 detection: hi-words of first 64 entries all zero => int64
__device__ inline int is64_ballot(const void* p) {
    const int* p32 = (const int*)p;
    int lane = threadIdx.x & 63;
    int ok = (p32[2 * lane + 1] == 0) ? 1 : 0;
    unsigned long long m = __ballot(ok);
    return m == ~0ULL ? 1 : 0;
}

// ---------------------------------------------------------------------------
// ws layout (CSR path), bytes:
//   hbf[NN*FH] bf16 | ne[NN*FH] f32 (packed pairs int[E] staged here) |
//   dinv[NN] | cursor[NN+1] | bucket[E] | cc_blk[NBUCK*NCB] |
//   coarse[NBUCK+1] | coarse_cursor[NBUCK]
// Fallback (ws too small): h f32 | ne f32 | deg | flag  (round-1 scatter)
// ---------------------------------------------------------------------------

// ---------------- gemm role: 64 rows of hbf = bf16(x @ W_conv) --------------
__device__ void gemm_role(const float* __restrict__ x, const float* __restrict__ W,
                          unsigned short* __restrict__ hbf, int gb, char* smem) {
    unsigned short* Wt = (unsigned short*)smem;   // [col][k], pitch WP

    for (int i = threadIdx.x; i < FIN * FH; i += 256) {
        int k = i >> 6, c = i & 63;
        Wt[c * WP + k] = f2bf_hw(W[i]);
    }
    __syncthreads();

    const int wv = threadIdx.x >> 6;
    const int lane = threadIdx.x & 63;
    const int c = lane & 15;
    const int eg = lane >> 4;

    const int row0 = (gb * 4 + wv) * 16;
    int rowA = row0 + c;
    if (rowA >= NN) rowA = NN - 1;
    const float* aptr = x + (long long)rowA * FIN;

    f32x4 acc[4] = {{0,0,0,0},{0,0,0,0},{0,0,0,0},{0,0,0,0}};

#pragma unroll
    for (int kk = 0; kk < 8; ++kk) {
        const int kbase = kk * 32 + eg * 8;
        float4 f0 = *(const float4*)(aptr + kbase);
        float4 f1 = *(const float4*)(aptr + kbase + 4);
        short8x a;
        a[0] = (short)f2bf_hw(f0.x); a[1] = (short)f2bf_hw(f0.y);
        a[2] = (short)f2bf_hw(f0.z); a[3] = (short)f2bf_hw(f0.w);
        a[4] = (short)f2bf_hw(f1.x); a[5] = (short)f2bf_hw(f1.y);
        a[6] = (short)f2bf_hw(f1.z); a[7] = (short)f2bf_hw(f1.w);
#pragma unroll
        for (int cb = 0; cb < 4; ++cb) {
            short8x b = *(const short8x*)(&Wt[(cb * 16 + c) * WP + kbase]);
            acc[cb] = __builtin_amdgcn_mfma_f32_16x16x32_bf16(a, b, acc[cb], 0, 0, 0);
        }
    }

#pragma unroll
    for (int cb = 0; cb < 4; ++cb) {
#pragma unroll
        for (int r = 0; r < 4; ++r) {
            int rowO = row0 + eg * 4 + r;
            if (rowO < NN)
                hbf[(long long)rowO * FH + cb * 16 + c] = f2bf_hw(acc[cb][r]);
        }
    }
}

// ---------------- count role: per-block private histogram slice -------------
__device__ void count_role(const void* __restrict__ ei, int* __restrict__ cc_blk,
                           int E, int cb, char* smem) {
    int* hist = (int*)smem;
    const int t = threadIdx.x;
    hist[t] = 0;
    __syncthreads();
    const int is64 = is64_ballot(ei);
    for (long long e = (long long)cb * 256 + t; e < E; e += (long long)NCB * 256) {
        int d = (int)load_idx(ei, (long long)E + e, is64);
        atomicAdd(&hist[(unsigned)d / BNODES], 1);
    }
    __syncthreads();
    cc_blk[t * NCB + cb] = hist[t];   // [bucket][block], no global atomics
}

// ---------------- part role: coarse partition with packed writes ------------
__device__ void part_role(const void* __restrict__ ei, int* __restrict__ coarse_cursor,
                          int* __restrict__ pairs, int E, int pb, char* smem) {
    int* hist = (int*)smem;
    int* blkoff = hist + NBUCK;
    const int t = threadIdx.x;
    hist[t] = 0;
    __syncthreads();
    const int is64 = is64_ballot(ei);
    const long long base = (long long)pb * P1_CH;

    int pkv[16], bkt[16], rnk[16];
#pragma unroll
    for (int i = 0; i < 16; ++i) {
        long long e = base + i * 256 + t;
        if (e < E) {
            int s = (int)load_idx(ei, e, is64);
            int d = (int)load_idx(ei, (long long)E + e, is64);
            int b = (int)((unsigned)d / BNODES);
            int dl = d - b * BNODES;
            pkv[i] = s | (dl << 17);
            bkt[i] = b;
            rnk[i] = atomicAdd(&hist[b], 1);
        } else {
            bkt[i] = -1;
        }
    }
    __syncthreads();
    blkoff[t] = atomicAdd(&coarse_cursor[t], hist[t]);
    __syncthreads();
#pragma unroll
    for (int i = 0; i < 16; ++i) {
        if (bkt[i] >= 0)
            pairs[blkoff[bkt[i]] + rnk[i]] = pkv[i];
    }
}

// ---------------- place role: degree count + scan -> cursor/dinv, place -----
__device__ void place_role(const int* __restrict__ pairs, const int* __restrict__ coarse,
                           int* __restrict__ cursor, float* __restrict__ dinv,
                           int* __restrict__ bucket, int b, char* smem) {
    int* cnt = (int*)smem;
    int* nstart = cnt + BNODES;
    int* wsum = nstart + BNODES + 1;
    const int t = threadIdx.x;
    const int lane = t & 63, w = t >> 6;
    const int g0 = b * BNODES;
    const int nb = (NN - g0 < BNODES) ? (NN - g0) : BNODES;
    const int lo = coarse[b], hi = coarse[b + 1];

    for (int j = t; j < nb; j += 256) cnt[j] = 0;
    __syncthreads();

    for (int i = lo + t; i < hi; i += 256)
        atomicAdd(&cnt[pairs[i] >> 17], 1);
    __syncthreads();

    const int i0 = 2 * t, i1 = 2 * t + 1;
    const int v0 = (i0 < nb) ? cnt[i0] : 0;
    const int v1 = (i1 < nb) ? cnt[i1] : 0;
    const int s = v0 + v1;
    int incl = s;
#pragma unroll
    for (int m = 1; m < 64; m <<= 1) {
        int u = __shfl_up(incl, m, 64);
        if (lane >= m) incl += u;
    }
    if (lane == 63) wsum[w] = incl;
    __syncthreads();
    int woff = 0;
    for (int i = 0; i < w; ++i) woff += wsum[i];
    const int ex = woff + incl - s;
    if (i0 <= nb) nstart[i0] = ex;
    if (i1 <= nb) nstart[i1] = ex + v0;
    __syncthreads();

    for (int j = t; j <= nb; j += 256) {
        int g = g0 + j;
        if (g <= NN) cursor[g] = lo + nstart[j];
    }
    for (int j = t; j < nb; j += 256)
        dinv[g0 + j] = rsqrtf(1.0f + (float)(nstart[j + 1] - nstart[j]));

    for (int j = t; j < nb; j += 256) cnt[j] = 0;
    __syncthreads();
    for (int i = lo + t; i < hi; i += 256) {
        int p = pairs[i];
        int local = p >> 17;
        int r = atomicAdd(&cnt[local], 1);
        bucket[lo + nstart[local] + r] = p & SRCMASK;
    }
}

// ---------------- fused kernels (block-range dispatch) ----------------------
__global__ __launch_bounds__(256) void fused1_kernel(const float* __restrict__ x,
                                                     const float* __restrict__ W,
                                                     unsigned short* __restrict__ hbf,
                                                     const void* __restrict__ ei,
                                                     int* __restrict__ cc_blk, int E) {
    __shared__ __align__(16) char smem[FH * WP * 2];
    const int b = blockIdx.x;
    if (b < GB3) gemm_role(x, W, hbf, b, smem);
    else         count_role(ei, cc_blk, E, b - GB3, smem);
}

__global__ __launch_bounds__(256) void fused2_kernel(const float* __restrict__ x,
                                                     const float* __restrict__ W,
                                                     unsigned short* __restrict__ hbf,
                                                     const void* __restrict__ ei,
                                                     int* __restrict__ coarse_cursor,
                                                     int* __restrict__ pairs, int E) {
    __shared__ __align__(16) char smem[FH * WP * 2];
    const int b = blockIdx.x;
    if (b < GB3) gemm_role(x, W, hbf, GB3 + b, smem);
    else         part_role(ei, coarse_cursor, pairs, E, b - GB3, smem);
}

__global__ __launch_bounds__(256) void fused3_kernel(const float* __restrict__ x,
                                                     const float* __restrict__ W,
                                                     unsigned short* __restrict__ hbf,
                                                     const int* __restrict__ pairs,
                                                     const int* __restrict__ coarse,
                                                     int* __restrict__ cursor,
                                                     float* __restrict__ dinv,
                                                     int* __restrict__ bucket) {
    __shared__ __align__(16) char smem[FH * WP * 2];
    const int b = blockIdx.x;
    if (b < GB3) gemm_role(x, W, hbf, 2 * GB3 + b, smem);
    else         place_role(pairs, coarse, cursor, dinv, bucket, b - GB3, smem);
}

// scan of summed per-block histograms -> coarse[257], coarse_cursor[256]
__global__ __launch_bounds__(256) void coarse_scan_kernel(const int* __restrict__ cc_blk,
                                                          int* __restrict__ coarse,
                                                          int* __restrict__ coarse_cursor) {
    const int t = threadIdx.x;
    const int lane = t & 63, w = t >> 6;
    int v = 0;
    const int* row = cc_blk + t * NCB;
    for (int b = 0; b < NCB; ++b) v += row[b];
    int incl = v;
#pragma unroll
    for (int m = 1; m < 64; m <<= 1) {
        int u = __shfl_up(incl, m, 64);
        if (lane >= m) incl += u;
    }
    __shared__ int wsum[4];
    if (lane == 63) wsum[w] = incl;
    __syncthreads();
    int woff = 0;
    for (int i = 0; i < w; ++i) woff += wsum[i];
    int ex = woff + incl - v;
    coarse[t] = ex;
    coarse_cursor[t] = ex;
    if (t == 255) coarse[NBUCK] = ex + v;   // = E
}

// one wave per node, 8 edges in flight (proven R6/R9 form)
__global__ __launch_bounds__(256) void gather8_kernel(const unsigned short* __restrict__ hbf,
                                                      const float* __restrict__ dinv,
                                                      const int* __restrict__ cursor,
                                                      const int* __restrict__ bucket,
                                                      const float* __restrict__ b_conv,
                                                      float* __restrict__ ne) {
    const int node = blockIdx.x * 4 + (threadIdx.x >> 6);
    if (node >= NN) return;
    const int lane = threadIdx.x & 63;
    const int sub = lane & 7;
    const int eg = lane >> 3;

    const int base = cursor[node];
    const int end  = cursor[node + 1];
    const float dd = dinv[node];

    float acc[8] = {0,0,0,0,0,0,0,0};
    for (int k = base + eg; k < end; k += 8) {
        int s = bucket[k];
        float nrm = dinv[s] * dd;
        short8x hv = *(const short8x*)(hbf + (long long)s * FH + sub * 8);
#pragma unroll
        for (int j = 0; j < 8; ++j)
            acc[j] += bf2f((unsigned short)hv[j]) * nrm;
    }
#pragma unroll
    for (int m = 8; m < 64; m <<= 1) {
#pragma unroll
        for (int j = 0; j < 8; ++j) acc[j] += __shfl_xor(acc[j], m);
    }
    if (eg == 0) {
        short8x hs = *(const short8x*)(hbf + (long long)node * FH + sub * 8);
        float r[8];
#pragma unroll
        for (int j = 0; j < 8; ++j) {
            float v = acc[j] + bf2f((unsigned short)hs[j]) * dd * dd + b_conv[sub * 8 + j];
            r[j] = v >= 0.f ? v : NEG * v;
        }
        float4* o = (float4*)(ne + (long long)node * FH + sub * 8);
        o[0] = make_float4(r[0], r[1], r[2], r[3]);
        o[1] = make_float4(r[4], r[5], r[6], r[7]);
    }
}

// ------------------------- MLP head -----------------------------------------
__global__ __launch_bounds__(256) void mlp_kernel(const float* __restrict__ ne,
                                                  const void* __restrict__ idx,
                                                  const float* __restrict__ W1,
                                                  const float* __restrict__ b1,
                                                  const float* __restrict__ W2,
                                                  const float* __restrict__ b2,
                                                  float* __restrict__ out,
                                                  int B) {
    const int lane = threadIdx.x & 63;
    const int wid = threadIdx.x >> 6;
    const int is64 = is64_ballot(idx);

    float w1a[16], w1b[16], b1r[16], w2r[16];
#pragma unroll
    for (int o = 0; o < 16; ++o) {
        w1a[o] = W1[lane * 16 + o];
        w1b[o] = W1[(64 + lane) * 16 + o];
        b1r[o] = b1[o];
        w2r[o] = W2[o];
    }
    const float b2v = b2[0];

    for (int pair = blockIdx.x * 4 + wid; pair < B; pair += gridDim.x * 4) {
        long long i0 = load_idx(idx, 2LL * pair, is64);
        long long i1 = load_idx(idx, 2LL * pair + 1, is64);
        float a = ne[i0 * FH + lane];
        float b = ne[i1 * FH + lane];

        float acc[16];
#pragma unroll
        for (int o = 0; o < 16; ++o) acc[o] = a * w1a[o] + b * w1b[o];
#pragma unroll
        for (int m = 1; m < 64; m <<= 1) {
#pragma unroll
            for (int o = 0; o < 16; ++o) acc[o] += __shfl_xor(acc[o], m, 64);
        }
        if (lane == 0) {
            float s = b2v;
#pragma unroll
            for (int o = 0; o < 16; ++o) {
                float z = acc[o] + b1r[o];
                z = z >= 0.f ? z : NEG * z;
                s += z * w2r[o];
            }
            out[pair] = 1.f / (1.f + expf(-s));
        }
    }
}

// ------------------------- fallback (round-1) path --------------------------

__global__ void detect_kernel(const int* __restrict__ ei32, int* __restrict__ flag) {
    if (blockIdx.x == 0 && threadIdx.x == 0) {
        int ok = 1;
        for (int k = 0; k < 64; ++k)
            if (ei32[2 * k + 1] != 0) { ok = 0; break; }
        *flag = ok;
    }
}

__global__ __launch_bounds__(256) void gemm_kernel(const float* __restrict__ x,
                                                   const float* __restrict__ W,
                                                   float* __restrict__ h) {
    __shared__ float xs[4 * FIN];
    __shared__ float part[4][4][FH];

    const int col = threadIdx.x & 63;
    const int kseg = threadIdx.x >> 6;

    float wreg[64];
#pragma unroll
    for (int kk = 0; kk < 64; ++kk)
        wreg[kk] = W[(kseg * 64 + kk) * FH + col];

    for (int row0 = blockIdx.x * 4; row0 < NN; row0 += gridDim.x * 4) {
        const float4* xv = (const float4*)(x + (long long)row0 * FIN);
        ((float4*)xs)[threadIdx.x] = xv[threadIdx.x];
        __syncthreads();

        float acc[4] = {0.f, 0.f, 0.f, 0.f};
#pragma unroll
        for (int kk = 0; kk < 64; ++kk) {
            const float w = wreg[kk];
            const int k = kseg * 64 + kk;
#pragma unroll
            for (int r = 0; r < 4; ++r)
                acc[r] += xs[r * FIN + k] * w;
        }
#pragma unroll
        for (int r = 0; r < 4; ++r) part[r][kseg][col] = acc[r];
        __syncthreads();

        const int row = threadIdx.x >> 6;
        float s = part[row][0][col] + part[row][1][col] + part[row][2][col] + part[row][3][col];
        h[(long long)(row0 + row) * FH + col] = s;
        __syncthreads();
    }
}

__global__ __launch_bounds__(256) void init_kernel(float* __restrict__ ne,
                                                   float* __restrict__ deg,
                                                   const float* __restrict__ b_conv) {
    int idx = blockIdx.x * 256 + threadIdx.x;
    if (idx < NN * FH) ne[idx] = b_conv[idx & (FH - 1)];
    if (idx < NN) deg[idx] = 1.0f;
}

__global__ __launch_bounds__(256) void deg_kernel(const void* __restrict__ ei,
                                                  float* __restrict__ deg,
                                                  int E, const int* __restrict__ flag) {
    int e = blockIdx.x * 256 + threadIdx.x;
    if (e >= E) return;
    long long d = load_idx(ei, (long long)E + e, *flag);
    atomicAdd(&deg[d], 1.0f);
}

__global__ __launch_bounds__(256) void rsqrt_kernel(float* __restrict__ deg) {
    int i = blockIdx.x * 256 + threadIdx.x;
    if (i < NN) deg[i] = rsqrtf(deg[i]);
}

__global__ __launch_bounds__(256) void selfloop_kernel(const float* __restrict__ h,
                                                       const float* __restrict__ dinv,
                                                       float* __restrict__ ne) {
    int idx = blockIdx.x * 256 + threadIdx.x;
    if (idx >= NN * FH) return;
    int i = idx >> 6;
    float di = dinv[i];
    ne[idx] += h[idx] * di * di;
}

__global__ __launch_bounds__(256) void edge_agg_kernel(const void* __restrict__ ei,
                                                       const float* __restrict__ dinv,
                                                       const float* __restrict__ h,
                                                       float* __restrict__ ne,
                                                       int E, const int* __restrict__ flag) {
    long long t = (long long)blockIdx.x * 256 + threadIdx.x;
    long long e = t >> 4;
    int sub = (int)(t & 15);
    if (e >= E) return;
    int is64 = *flag;
    long long s = load_idx(ei, e, is64);
    long long d = load_idx(ei, (long long)E + e, is64);
    float nrm = dinv[s] * dinv[d];
    float4 hv = *(const float4*)(h + s * FH + sub * 4);
    float* np_ = ne + d * FH + sub * 4;
    atomicAdd(np_ + 0, hv.x * nrm);
    atomicAdd(np_ + 1, hv.y * nrm);
    atomicAdd(np_ + 2, hv.z * nrm);
    atomicAdd(np_ + 3, hv.w * nrm);
}

__global__ __launch_bounds__(256) void mlp_fb_kernel(const float* __restrict__ ne,
                                                     const void* __restrict__ idx,
                                                     const float* __restrict__ W1,
                                                     const float* __restrict__ b1,
                                                     const float* __restrict__ W2,
                                                     const float* __restrict__ b2,
                                                     float* __restrict__ out,
                                                     int B, const int* __restrict__ flag) {
    const int lane = threadIdx.x & 63;
    const int wid = threadIdx.x >> 6;

    float w1a[16], w1b[16], b1r[16], w2r[16];
#pragma unroll
    for (int o = 0; o < 16; ++o) {
        w1a[o] = W1[lane * 16 + o];
        w1b[o] = W1[(64 + lane) * 16 + o];
        b1r[o] = b1[o];
        w2r[o] = W2[o];
    }
    const float b2v = b2[0];
    const int is64 = *flag;

    for (int pair = blockIdx.x * 4 + wid; pair < B; pair += gridDim.x * 4) {
        long long i0 = load_idx(idx, 2LL * pair, is64);
        long long i1 = load_idx(idx, 2LL * pair + 1, is64);
        float a = ne[i0 * FH + lane];
        float b = ne[i1 * FH + lane];
        a = a >= 0.f ? a : NEG * a;
        b = b >= 0.f ? b : NEG * b;

        float acc[16];
#pragma unroll
        for (int o = 0; o < 16; ++o) acc[o] = a * w1a[o] + b * w1b[o];
#pragma unroll
        for (int m = 1; m < 64; m <<= 1) {
#pragma unroll
            for (int o = 0; o < 16; ++o) acc[o] += __shfl_xor(acc[o], m, 64);
        }
        if (lane == 0) {
            float s = b2v;
#pragma unroll
            for (int o = 0; o < 16; ++o) {
                float z = acc[o] + b1r[o];
                z = z >= 0.f ? z : NEG * z;
                s += z * w2r[o];
            }
            out[pair] = 1.f / (1.f + expf(-s));
        }
    }
}

extern "C" void kernel_launch(void* const* d_in, const int* in_sizes, int n_in,
                              void* d_out, int out_size, void* d_ws, size_t ws_size,
                              hipStream_t stream) {
    const float* x      = (const float*)d_in[0];
    const void*  ei     = d_in[1];
    const void*  index  = d_in[2];
    const float* W_conv = (const float*)d_in[3];
    const float* b_conv = (const float*)d_in[4];
    const float* W1     = (const float*)d_in[5];
    const float* b1     = (const float*)d_in[6];
    const float* W2     = (const float*)d_in[7];
    const float* b2     = (const float*)d_in[8];
    float* out = (float*)d_out;

    const int E = in_sizes[1] / 2;   // 1.6M
    const int B = in_sizes[2] / 2;   // 16384

    const size_t need_new = (size_t)NN * FH * 2
                          + ((size_t)NN * FH + NN + (NN + 1) + (size_t)E
                             + NBUCK * NCB + (NBUCK + 1) + NBUCK) * 4;

    if (ws_size >= need_new) {
        unsigned short* hbf = (unsigned short*)d_ws;
        float* ne       = (float*)(hbf + (long long)NN * FH);
        float* dinv     = ne + (long long)NN * FH;
        int*   cursor   = (int*)(dinv + NN);          // NN+1 entries
        int*   bucket   = cursor + (NN + 1);
        int*   cc_blk   = bucket + E;                 // NBUCK*NCB
        int*   coarse   = cc_blk + NBUCK * NCB;       // NBUCK+1
        int*   coarse_cursor = coarse + (NBUCK + 1);
        int*   pairs    = (int*)ne;                   // staged in dead ne buffer

        const int npart = (E + P1_CH - 1) / P1_CH;

        fused1_kernel<<<GB3 + NCB, 256, 0, stream>>>(x, W_conv, hbf, ei, cc_blk, E);
        coarse_scan_kernel<<<1, 256, 0, stream>>>(cc_blk, coarse, coarse_cursor);
        fused2_kernel<<<GB3 + npart, 256, 0, stream>>>(x, W_conv, hbf, ei, coarse_cursor, pairs, E);
        fused3_kernel<<<GB3 + NBUCK, 256, 0, stream>>>(x, W_conv, hbf, pairs, coarse, cursor, dinv, bucket);
        gather8_kernel<<<(NN + 3) / 4, 256, 0, stream>>>(hbf, dinv, cursor, bucket, b_conv, ne);
        mlp_kernel<<<512, 256, 0, stream>>>(ne, index, W1, b1, W2, b2, out, B);
    } else {
        // fallback: round-1 atomic scatter (fp32)
        float* h   = (float*)d_ws;
        float* ne  = h + (long long)NN * FH;
        float* deg = ne + (long long)NN * FH;
        int* flag  = (int*)(deg + NN);

        detect_kernel<<<1, 64, 0, stream>>>((const int*)ei, flag);
        init_kernel<<<(NN * FH + 255) / 256, 256, 0, stream>>>(ne, deg, b_conv);
        gemm_kernel<<<2048, 256, 0, stream>>>(x, W_conv, h);
        deg_kernel<<<(E + 255) / 256, 256, 0, stream>>>(ei, deg, E, flag);
        rsqrt_kernel<<<(NN + 255) / 256, 256, 0, stream>>>(deg);
        selfloop_kernel<<<(NN * FH + 255) / 256, 256, 0, stream>>>(h, deg, ne);
        edge_agg_kernel<<<(int)(((long long)E * 16 + 255) / 256), 256, 0, stream>>>(ei, deg, h, ne, E, flag);
        mlp_fb_kernel<<<512, 256, 0, stream>>>(ne, index, W1, b1, W2, b2, out, B, flag);
    }
}